// Round 8
// baseline (48.647 us; speedup 1.0000x reference)
//
#include <hip/hip_runtime.h>
#include <math.h>

#define NQ 8
#define DEPTH 3
#define FDIM 16
#define HDIM 256
#define WAVES_PER_BLOCK 4
#define THREADS (WAVES_PER_BLOCK * 64)
#define NGATE (NQ * DEPTH)        // 24 (RZ,RY) pairs

// ---------------- cross-lane xor shuffles ----------------
template<int CTRL>
__device__ __forceinline__ float dpp1(float v) {
    return __int_as_float(__builtin_amdgcn_update_dpp(
        0, __float_as_int(v), CTRL, 0xF, 0xF, true));
}

// single-DPP xor masks used by wred (VALU, lowest latency)
template<int M4>
__device__ __forceinline__ float shuf4(float v) {
    if constexpr (M4 == 1)  return dpp1<0xB1>(v);   // quad_perm xor1
    else if constexpr (M4 == 2)  return dpp1<0x4E>(v);   // quad_perm xor2
    else if constexpr (M4 == 4)  return dpp1<0x1B>(dpp1<0x141>(v)); // xor3 o xor7
    else if constexpr (M4 == 8)  return dpp1<0x128>(v);  // row_ror:8 == xor8
    else return v;
}

// general 6-bit xor shuffle on the LDS pipe (0 VALU slots):
// ds_swizzle BitMode for masks 1..31, ds_bpermute for masks with bit5 set.
template<int ML>
__device__ __forceinline__ float shuf(float v, int lane) {
    if constexpr (ML == 0) {
        return v;
    } else if constexpr (ML >= 32) {
        int addr = (lane ^ ML) << 2;   // CSE'd across the 8 uses per gate
        return __int_as_float(__builtin_amdgcn_ds_bpermute(addr, __float_as_int(v)));
    } else {
        return __int_as_float(__builtin_amdgcn_ds_swizzle(
            __float_as_int(v), (ML << 10) | 0x1F));   // xor=ML, and=0x1F
    }
}

// full 64-lane sum, all lanes receive the total.
// permlane*_swap trick: r[0]+r[1] == v + v[lane^K] for every lane (no select).
__device__ __forceinline__ float wred(float v, int lane) {
    v += shuf4<1>(v);
    v += shuf4<2>(v);
    v += shuf4<4>(v);
    v += shuf4<8>(v);
#if __has_builtin(__builtin_amdgcn_permlane16_swap)
    {
        auto r = __builtin_amdgcn_permlane16_swap(__float_as_int(v), __float_as_int(v), false, false);
        v = __int_as_float(r[0]) + __int_as_float(r[1]);
    }
#else
    v += __shfl_xor(v, 16, 64);
#endif
#if __has_builtin(__builtin_amdgcn_permlane32_swap)
    {
        auto r = __builtin_amdgcn_permlane32_swap(__float_as_int(v), __float_as_int(v), false, false);
        v = __int_as_float(r[0]) + __int_as_float(r[1]);
    }
#else
    v += __shfl_xor(v, 32, 64);
#endif
    return v;
}

__device__ __forceinline__ float fast_tanh(float y) {
    float ex = __expf(2.f * y);                       // inf for large y -> t=1
    return 1.f - 2.f * __builtin_amdgcn_rcpf(ex + 1.f);
}

// ================= K1: encoder -> u = tanh(.)/4  (8 floats per row) =================
__global__ __launch_bounds__(THREADS) void enc_kernel(
    const float* __restrict__ x,     // (B,16)
    const float* __restrict__ w1,    // (256,16)
    const float* __restrict__ b1,    // (256)
    const float* __restrict__ w2,    // (8,256)
    const float* __restrict__ b2,    // (8)
    float* __restrict__ uo,          // (B,8) workspace
    int B)
{
    const int t = threadIdx.x;
    const int lane = t & 63;
    const int row  = blockIdx.x * WAVES_PER_BLOCK + (t >> 6);
    if (row >= B) return;

    const float4* xp = (const float4*)(x + row * FDIM);
    float4 x0 = xp[0], x1 = xp[1], x2 = xp[2], x3 = xp[3];

    float hreg[4];
#pragma unroll
    for (int m = 0; m < 4; m++) {
        int j = lane + 64 * m;
        const float4* wp = (const float4*)(w1 + j * FDIM);
        float4 wa = wp[0], wb = wp[1], wc = wp[2], wd = wp[3];
        float acc = b1[j];
        acc = fmaf(x0.x, wa.x, acc); acc = fmaf(x0.y, wa.y, acc);
        acc = fmaf(x0.z, wa.z, acc); acc = fmaf(x0.w, wa.w, acc);
        acc = fmaf(x1.x, wb.x, acc); acc = fmaf(x1.y, wb.y, acc);
        acc = fmaf(x1.z, wb.z, acc); acc = fmaf(x1.w, wb.w, acc);
        acc = fmaf(x2.x, wc.x, acc); acc = fmaf(x2.y, wc.y, acc);
        acc = fmaf(x2.z, wc.z, acc); acc = fmaf(x2.w, wc.w, acc);
        acc = fmaf(x3.x, wd.x, acc); acc = fmaf(x3.y, wd.y, acc);
        acc = fmaf(x3.z, wd.z, acc); acc = fmaf(x3.w, wd.w, acc);
        hreg[m] = fmaxf(acc, 0.f);
    }

    float myu = 0.f;
#pragma unroll
    for (int q = 0; q < NQ; q++) {
        float a = 0.f;
#pragma unroll
        for (int m = 0; m < 4; m++)
            a = fmaf(hreg[m], w2[q * HDIM + lane + 64 * m], a);
        a = wred(a, lane);
        float u = 0.25f * fast_tanh(a + b2[q]);
        if (lane == q) myu = u;
    }
    if (lane < NQ) uo[row * NQ + lane] = myu;
}

// ---------------- relabeled gate ----------------
// Physical storage never permuted. Layer-l gates use pair-mask M = A^l*e_b and
// parity row R = row_b(A^{-l}), both 8-bit compile-time constants over
// x = (hi<<6)|lane.  RZ: amp *= (cz + i*sgz), sgz = p? sz : -sz.
// RY: amp = cy*amp + sgy*partner, partner at x ^ M, sgy = p? sy : -sy.
template<int M, int R>
__device__ __forceinline__ void gate2(float (&sr)[4], float (&si)[4],
                                      float cz, float szv, float cy, float sy,
                                      int lane) {
    constexpr int ML = M & 63, MH = (M >> 6) & 3;
    constexpr int RL = R & 63, RH = (R >> 6) & 3;
    bool p0;
    if constexpr (RL == 0)                 p0 = false;
    else if constexpr ((RL & (RL-1)) == 0) p0 = (lane & RL) != 0;
    else                                   p0 = (__popc(lane & RL) & 1) != 0;
    float sgz = p0 ? szv : -szv;
    float sgy = p0 ? sy  : -sy;
    // RZ (diagonal phase)
#pragma unroll
    for (int hi = 0; hi < 4; hi++) {
        const bool f = (__builtin_popcount(hi & RH) & 1) != 0;   // folds per-hi
        float z = f ? -sgz : sgz;
        float nr = fmaf(sr[hi], cz, -(si[hi] * z));
        float ni = fmaf(si[hi], cz,  (sr[hi] * z));
        sr[hi] = nr; si[hi] = ni;
    }
    // RY partners from post-RZ values
    float pr[4], pi[4];
#pragma unroll
    for (int hi = 0; hi < 4; hi++) {
        pr[hi] = shuf<ML>(sr[hi ^ MH], lane);
        pi[hi] = shuf<ML>(si[hi ^ MH], lane);
    }
#pragma unroll
    for (int hi = 0; hi < 4; hi++) {
        const bool f = (__builtin_popcount(hi & RH) & 1) != 0;
        float yv = f ? -sgy : sgy;
        sr[hi] = fmaf(yv, pr[hi], cy * sr[hi]);
        si[hi] = fmaf(yv, pi[hi], cy * si[hi]);
    }
}

// ================= K2: circuit + decoder =================
__global__ __launch_bounds__(THREADS, 8) void circ_kernel(
    const float* __restrict__ uo,    // (B,8)
    const float* __restrict__ qp,    // (48)
    const float* __restrict__ dw1,   // (256,1)
    const float* __restrict__ db1,   // (256)
    const float* __restrict__ dw2,   // (1,256)
    const float* __restrict__ db2,   // (1)
    float* __restrict__ out, int B)
{
    __shared__ float4 sG4[NGATE];    // (cz,sz,cy,sy) per gate; gate g: qp[2g], qp[2g+1]

    const int t = threadIdx.x;
    if (t < 2 * NGATE) {
        float s, c;
        __sincosf(qp[t] * 0.5f, &s, &c);
        float* p = (float*)&sG4[t >> 1] + 2 * (t & 1);
        p[0] = c; p[1] = s;
    }
    __syncthreads();

    const int lane = t & 63;
    const int row  = blockIdx.x * WAVES_PER_BLOCK + (t >> 6);
    if (row >= B) return;

    // ---- load u (revolutions), build product state ----
    const float4* up = (const float4*)(uo + row * NQ);
    float4 u0 = up[0], u1 = up[1];   // u0: q0..3, u1: q4..7

    float c00, s00, c01, s01;
    asm("v_sin_f32 %0, %1" : "=v"(s00) : "v"(u0.x));
    asm("v_cos_f32 %0, %1" : "=v"(c00) : "v"(u0.x));
    asm("v_sin_f32 %0, %1" : "=v"(s01) : "v"(u0.y));
    asm("v_cos_f32 %0, %1" : "=v"(c01) : "v"(u0.y));

    float pl = 1.f;
    {
        float uv[6] = {u0.z, u0.w, u1.x, u1.y, u1.z, u1.w};   // q=2..7, bit 7-q = 5..0
#pragma unroll
        for (int q = 2; q < 8; q++) {
            float sv, cv;
            asm("v_sin_f32 %0, %1" : "=v"(sv) : "v"(uv[q - 2]));
            asm("v_cos_f32 %0, %1" : "=v"(cv) : "v"(uv[q - 2]));
            pl *= ((lane >> (7 - q)) & 1) ? sv : cv;
        }
    }

    float sr[4], si[4];
    sr[0] = pl * c01 * c00;
    sr[1] = pl * s01 * c00;
    sr[2] = pl * c01 * s00;
    sr[3] = pl * s01 * s00;
#pragma unroll
    for (int hi = 0; hi < 4; hi++) si[hi] = 0.f;

    // ---- circuit: CX chains folded into per-layer masks (GF(2) relabeling) ----
    // A cols: C1 03 06 0C 18 30 60 C0 ; A^2 cols: 61 C2 05 0A 14 28 50 A0
    // A^-1 rows: FF FE FC F8 F0 E0 C0 7F ; A^-2 rows: AA 55 AB 57 AF 5F BF D5
#define GATE(L, Q, MM, RR) { float4 g4 = sG4[(L)*8 + (Q)]; \
        gate2<MM, RR>(sr, si, g4.x, g4.y, g4.z, g4.w, lane); }
    // layer 0 (identity labeling)
    GATE(0,0,0x80,0x80) GATE(0,1,0x40,0x40) GATE(0,2,0x20,0x20) GATE(0,3,0x10,0x10)
    GATE(0,4,0x08,0x08) GATE(0,5,0x04,0x04) GATE(0,6,0x02,0x02) GATE(0,7,0x01,0x01)
    // layer 1 (masks = cols of A, parities = rows of A^-1)
    GATE(1,0,0xC0,0x7F) GATE(1,1,0x60,0xC0) GATE(1,2,0x30,0xE0) GATE(1,3,0x18,0xF0)
    GATE(1,4,0x0C,0xF8) GATE(1,5,0x06,0xFC) GATE(1,6,0x03,0xFE) GATE(1,7,0xC1,0xFF)
    // layer 2 (masks = cols of A^2, parities = rows of A^-2)
    GATE(2,0,0xA0,0xD5) GATE(2,1,0x50,0xBF) GATE(2,2,0x28,0x5F) GATE(2,3,0x14,0xAF)
    GATE(2,4,0x0A,0x57) GATE(2,5,0x05,0xAB) GATE(2,6,0xC2,0x55) GATE(2,7,0x61,0xAA)
#undef GATE

    // ---- <Z_0> with final labeling: sign = parity(x & 0x4C) (row7 of A^-3) ----
    float m0 = sr[0]*sr[0] + si[0]*si[0] + sr[2]*sr[2] + si[2]*si[2]; // hi&1==0
    float m1 = sr[1]*sr[1] + si[1]*si[1] + sr[3]*sr[3] + si[3]*si[3]; // hi&1==1
    bool pb = (__popc(lane & 0x0C) & 1) != 0;
    float e = pb ? (m1 - m0) : (m0 - m1);
    e = wred(e, lane);

    // ---- decoder ----
    float acc = 0.f;
#pragma unroll
    for (int m = 0; m < 4; m++) {
        int j = lane + 64 * m;
        float d = fmaxf(fmaf(e, dw1[j], db1[j]), 0.f);
        acc = fmaf(d, dw2[j], acc);
    }
    acc = wred(acc, lane);
    if (lane == 0) out[row] = 1.f / (1.f + __expf(-(acc + db2[0])));
}

extern "C" void kernel_launch(void* const* d_in, const int* in_sizes, int n_in,
                              void* d_out, int out_size, void* d_ws, size_t ws_size,
                              hipStream_t stream) {
    const float* x   = (const float*)d_in[0];
    const float* w1  = (const float*)d_in[1];
    const float* b1  = (const float*)d_in[2];
    const float* w2  = (const float*)d_in[3];
    const float* b2  = (const float*)d_in[4];
    const float* qp  = (const float*)d_in[5];
    const float* dw1 = (const float*)d_in[6];
    const float* db1 = (const float*)d_in[7];
    const float* dw2 = (const float*)d_in[8];
    const float* db2 = (const float*)d_in[9];
    float* out = (float*)d_out;
    float* uo  = (float*)d_ws;          // B*8 floats = 512 KB

    const int B = in_sizes[0] / FDIM;
    const int grid = (B + WAVES_PER_BLOCK - 1) / WAVES_PER_BLOCK;
    enc_kernel <<<grid, THREADS, 0, stream>>>(x, w1, b1, w2, b2, uo, B);
    circ_kernel<<<grid, THREADS, 0, stream>>>(uo, qp, dw1, db1, dw2, db2, out, B);
}

// Round 9
// 42.504 us; speedup vs baseline: 1.1445x; 1.1445x over previous
//
#include <hip/hip_runtime.h>
#include <math.h>

#define NQ 8
#define DEPTH 3
#define FDIM 16
#define HDIM 256
#define WAVES_PER_BLOCK 4
#define THREADS (WAVES_PER_BLOCK * 64)
#define NGATE (NQ * DEPTH)        // 24 (RZ,RY) pairs

// ---------------- cross-lane xor shuffles ----------------
template<int CTRL>
__device__ __forceinline__ float dpp1(float v) {
    return __int_as_float(__builtin_amdgcn_update_dpp(
        0, __float_as_int(v), CTRL, 0xF, 0xF, true));
}

// single-DPP xor masks used by wred (VALU, lowest latency)
template<int M4>
__device__ __forceinline__ float shuf4(float v) {
    if constexpr (M4 == 1)  return dpp1<0xB1>(v);   // quad_perm xor1
    else if constexpr (M4 == 2)  return dpp1<0x4E>(v);   // quad_perm xor2
    else if constexpr (M4 == 4)  return dpp1<0x1B>(dpp1<0x141>(v)); // xor3 o xor7
    else if constexpr (M4 == 8)  return dpp1<0x128>(v);  // row_ror:8 == xor8
    else return v;
}

// general 6-bit xor shuffle on the LDS pipe (0 VALU slots):
// ds_swizzle BitMode for masks 1..31, ds_bpermute for masks with bit5 set.
template<int ML>
__device__ __forceinline__ float shuf(float v, int lane) {
    if constexpr (ML == 0) {
        return v;
    } else if constexpr (ML >= 32) {
        int addr = (lane ^ ML) << 2;   // CSE'd across the 8 uses per gate
        return __int_as_float(__builtin_amdgcn_ds_bpermute(addr, __float_as_int(v)));
    } else {
        return __int_as_float(__builtin_amdgcn_ds_swizzle(
            __float_as_int(v), (ML << 10) | 0x1F));   // xor=ML, and=0x1F
    }
}

// full 64-lane sum, all lanes receive the total.
// permlane*_swap trick: r[0]+r[1] == v + v[lane^K] for every lane (no select).
__device__ __forceinline__ float wred(float v, int lane) {
    v += shuf4<1>(v);
    v += shuf4<2>(v);
    v += shuf4<4>(v);
    v += shuf4<8>(v);
#if __has_builtin(__builtin_amdgcn_permlane16_swap)
    {
        auto r = __builtin_amdgcn_permlane16_swap(__float_as_int(v), __float_as_int(v), false, false);
        v = __int_as_float(r[0]) + __int_as_float(r[1]);
    }
#else
    v += __shfl_xor(v, 16, 64);
#endif
#if __has_builtin(__builtin_amdgcn_permlane32_swap)
    {
        auto r = __builtin_amdgcn_permlane32_swap(__float_as_int(v), __float_as_int(v), false, false);
        v = __int_as_float(r[0]) + __int_as_float(r[1]);
    }
#else
    v += __shfl_xor(v, 32, 64);
#endif
    return v;
}

__device__ __forceinline__ float fast_tanh(float y) {
    float ex = __expf(2.f * y);                       // inf for large y -> t=1
    return 1.f - 2.f * __builtin_amdgcn_rcpf(ex + 1.f);
}

// ---------------- relabeled gate ----------------
// Physical storage never permuted. Layer-l gates use pair-mask M = A^l*e_b and
// parity row R = row_b(A^{-l}), both 8-bit compile-time constants over
// x = (hi<<6)|lane.  RZ: amp *= (cz + i*sgz), sgz = p? sz : -sz.
// RY: amp = cy*amp + sgy*partner, partner at x ^ M, sgy = p? sy : -sy.
template<int M, int R>
__device__ __forceinline__ void gate2(float (&sr)[4], float (&si)[4],
                                      float cz, float szv, float cy, float sy,
                                      int lane) {
    constexpr int ML = M & 63, MH = (M >> 6) & 3;
    constexpr int RL = R & 63, RH = (R >> 6) & 3;
    bool p0;
    if constexpr (RL == 0)                 p0 = false;
    else if constexpr ((RL & (RL-1)) == 0) p0 = (lane & RL) != 0;
    else                                   p0 = (__popc(lane & RL) & 1) != 0;
    float sgz = p0 ? szv : -szv;
    float sgy = p0 ? sy  : -sy;
    // RZ (diagonal phase)
#pragma unroll
    for (int hi = 0; hi < 4; hi++) {
        const bool f = (__builtin_popcount(hi & RH) & 1) != 0;   // folds per-hi
        float z = f ? -sgz : sgz;
        float nr = fmaf(sr[hi], cz, -(si[hi] * z));
        float ni = fmaf(si[hi], cz,  (sr[hi] * z));
        sr[hi] = nr; si[hi] = ni;
    }
    // RY partners from post-RZ values
    float pr[4], pi[4];
#pragma unroll
    for (int hi = 0; hi < 4; hi++) {
        pr[hi] = shuf<ML>(sr[hi ^ MH], lane);
        pi[hi] = shuf<ML>(si[hi ^ MH], lane);
    }
#pragma unroll
    for (int hi = 0; hi < 4; hi++) {
        const bool f = (__builtin_popcount(hi & RH) & 1) != 0;
        float yv = f ? -sgy : sgy;
        sr[hi] = fmaf(yv, pr[hi], cy * sr[hi]);
        si[hi] = fmaf(yv, pi[hi], cy * si[hi]);
    }
}

__global__ __launch_bounds__(THREADS, 8) void hqcl_kernel(
    const float* __restrict__ x,     // (B,16)
    const float* __restrict__ w1,    // (256,16)
    const float* __restrict__ b1,    // (256)
    const float* __restrict__ w2,    // (8,256)
    const float* __restrict__ b2,    // (8)
    const float* __restrict__ qp,    // (48)
    const float* __restrict__ dw1,   // (256,1)
    const float* __restrict__ db1,   // (256)
    const float* __restrict__ dw2,   // (1,256)
    const float* __restrict__ db2,   // (1)
    float* __restrict__ out, int B)
{
    __shared__ float4 sG4[NGATE];    // (cz,sz,cy,sy) per gate; gate g: qp[2g], qp[2g+1]

    const int t = threadIdx.x;
    if (t < 2 * NGATE) {
        float s, c;
        __sincosf(qp[t] * 0.5f, &s, &c);
        float* p = (float*)&sG4[t >> 1] + 2 * (t & 1);
        p[0] = c; p[1] = s;
    }
    __syncthreads();

    const int lane = t & 63;
    const int row  = blockIdx.x * WAVES_PER_BLOCK + (t >> 6);
    if (row >= B) return;

    // ---- encoder: h = relu(x @ W1^T + b1) ----
    // unroll 1: keep only one m-iteration's weight float4s live (hoist throttle,
    // the R7 spill source). TLP at 8 waves/SIMD hides the lost load ILP.
    const float4* xp = (const float4*)(x + row * FDIM);
    float4 x0 = xp[0], x1 = xp[1], x2 = xp[2], x3 = xp[3];

    float hreg[4];
#pragma unroll 1
    for (int m = 0; m < 4; m++) {
        int j = lane + 64 * m;
        const float4* wp = (const float4*)(w1 + j * FDIM);
        float4 wa = wp[0], wb = wp[1], wc = wp[2], wd = wp[3];
        float acc = b1[j];
        acc = fmaf(x0.x, wa.x, acc); acc = fmaf(x0.y, wa.y, acc);
        acc = fmaf(x0.z, wa.z, acc); acc = fmaf(x0.w, wa.w, acc);
        acc = fmaf(x1.x, wb.x, acc); acc = fmaf(x1.y, wb.y, acc);
        acc = fmaf(x1.z, wb.z, acc); acc = fmaf(x1.w, wb.w, acc);
        acc = fmaf(x2.x, wc.x, acc); acc = fmaf(x2.y, wc.y, acc);
        acc = fmaf(x2.z, wc.z, acc); acc = fmaf(x2.w, wc.w, acc);
        acc = fmaf(x3.x, wd.x, acc); acc = fmaf(x3.y, wd.y, acc);
        acc = fmaf(x3.z, wd.z, acc); acc = fmaf(x3.w, wd.w, acc);
        hreg[m] = fmaxf(acc, 0.f);
    }

    // ---- angles: u = tanh(h @ W2^T + b2)/4 revolutions, folded on the fly ----
    // unroll 1 stops the compiler hoisting all 32 w2 loads (R7's other spill
    // source). q is wave-uniform -> the branch below is s_cbranch, no
    // divergence, and no runtime-indexed array (rule #20: would go to scratch).
    float c00, s00, c01, s01;
    float pl = 1.f;
#pragma unroll 1
    for (int q = 0; q < NQ; q++) {
        const float* wq = w2 + q * HDIM + lane;
        float a = 0.f;
        a = fmaf(hreg[0], wq[0],   a);
        a = fmaf(hreg[1], wq[64],  a);
        a = fmaf(hreg[2], wq[128], a);
        a = fmaf(hreg[3], wq[192], a);
        a = wred(a, lane);
        float u = 0.25f * fast_tanh(a + b2[q]);
        float sv, cv;
        asm("v_sin_f32 %0, %1" : "=v"(sv) : "v"(u));
        asm("v_cos_f32 %0, %1" : "=v"(cv) : "v"(u));
        if (q == 0)      { c00 = cv; s00 = sv; }
        else if (q == 1) { c01 = cv; s01 = sv; }
        else             { pl *= ((lane >> (7 - q)) & 1) ? sv : cv; }
    }

    // ---- initial product state: amp x = hi*64 + lane ----
    float sr[4], si[4];
    sr[0] = pl * c01 * c00;
    sr[1] = pl * s01 * c00;
    sr[2] = pl * c01 * s00;
    sr[3] = pl * s01 * s00;
#pragma unroll
    for (int hi = 0; hi < 4; hi++) si[hi] = 0.f;

    // ---- circuit: CX chains folded into per-layer masks (GF(2) relabeling) ----
    // A cols: C1 03 06 0C 18 30 60 C0 ; A^2 cols: 61 C2 05 0A 14 28 50 A0
    // A^-1 rows: FF FE FC F8 F0 E0 C0 7F ; A^-2 rows: AA 55 AB 57 AF 5F BF D5
#define GATE(L, Q, MM, RR) { float4 g4 = sG4[(L)*8 + (Q)]; \
        gate2<MM, RR>(sr, si, g4.x, g4.y, g4.z, g4.w, lane); }
    // layer 0 (identity labeling)
    GATE(0,0,0x80,0x80) GATE(0,1,0x40,0x40) GATE(0,2,0x20,0x20) GATE(0,3,0x10,0x10)
    GATE(0,4,0x08,0x08) GATE(0,5,0x04,0x04) GATE(0,6,0x02,0x02) GATE(0,7,0x01,0x01)
    // layer 1 (masks = cols of A, parities = rows of A^-1)
    GATE(1,0,0xC0,0x7F) GATE(1,1,0x60,0xC0) GATE(1,2,0x30,0xE0) GATE(1,3,0x18,0xF0)
    GATE(1,4,0x0C,0xF8) GATE(1,5,0x06,0xFC) GATE(1,6,0x03,0xFE) GATE(1,7,0xC1,0xFF)
    // layer 2 (masks = cols of A^2, parities = rows of A^-2)
    GATE(2,0,0xA0,0xD5) GATE(2,1,0x50,0xBF) GATE(2,2,0x28,0x5F) GATE(2,3,0x14,0xAF)
    GATE(2,4,0x0A,0x57) GATE(2,5,0x05,0xAB) GATE(2,6,0xC2,0x55) GATE(2,7,0x61,0xAA)
#undef GATE

    // ---- <Z_0> with final labeling: sign = parity(x & 0x4C) (row7 of A^-3) ----
    float m0 = sr[0]*sr[0] + si[0]*si[0] + sr[2]*sr[2] + si[2]*si[2]; // hi&1==0
    float m1 = sr[1]*sr[1] + si[1]*si[1] + sr[3]*sr[3] + si[3]*si[3]; // hi&1==1
    bool pb = (__popc(lane & 0x0C) & 1) != 0;
    float e = pb ? (m1 - m0) : (m0 - m1);
    e = wred(e, lane);

    // ---- decoder ----
    float acc = 0.f;
#pragma unroll
    for (int m = 0; m < 4; m++) {
        int j = lane + 64 * m;
        float d = fmaxf(fmaf(e, dw1[j], db1[j]), 0.f);
        acc = fmaf(d, dw2[j], acc);
    }
    acc = wred(acc, lane);
    if (lane == 0) out[row] = 1.f / (1.f + __expf(-(acc + db2[0])));
}

extern "C" void kernel_launch(void* const* d_in, const int* in_sizes, int n_in,
                              void* d_out, int out_size, void* d_ws, size_t ws_size,
                              hipStream_t stream) {
    const float* x   = (const float*)d_in[0];
    const float* w1  = (const float*)d_in[1];
    const float* b1  = (const float*)d_in[2];
    const float* w2  = (const float*)d_in[3];
    const float* b2  = (const float*)d_in[4];
    const float* qp  = (const float*)d_in[5];
    const float* dw1 = (const float*)d_in[6];
    const float* db1 = (const float*)d_in[7];
    const float* dw2 = (const float*)d_in[8];
    const float* db2 = (const float*)d_in[9];
    float* out = (float*)d_out;

    const int B = in_sizes[0] / FDIM;
    const int grid = (B + WAVES_PER_BLOCK - 1) / WAVES_PER_BLOCK;
    hqcl_kernel<<<grid, THREADS, 0, stream>>>(x, w1, b1, w2, b2, qp, dw1, db1, dw2, db2, out, B);
}

// Round 10
// 39.221 us; speedup vs baseline: 1.2403x; 1.0837x over previous
//
#include <hip/hip_runtime.h>
#include <math.h>

#define NQ 8
#define DEPTH 3
#define FDIM 16
#define HDIM 256
#define WAVES_PER_BLOCK 4
#define THREADS (WAVES_PER_BLOCK * 64)
#define ROWS_PER_BLOCK (WAVES_PER_BLOCK * 2)
#define NGATE (NQ * DEPTH)        // 24 (RZ,RY) pairs

// ---------------- cross-lane xor shuffles ----------------
template<int CTRL>
__device__ __forceinline__ float dpp1(float v) {
    return __int_as_float(__builtin_amdgcn_update_dpp(
        0, __float_as_int(v), CTRL, 0xF, 0xF, true));
}

// single-DPP xor masks used by wred (VALU, lowest latency)
template<int M4>
__device__ __forceinline__ float shuf4(float v) {
    if constexpr (M4 == 1)  return dpp1<0xB1>(v);   // quad_perm xor1
    else if constexpr (M4 == 2)  return dpp1<0x4E>(v);   // quad_perm xor2
    else if constexpr (M4 == 4)  return dpp1<0x1B>(dpp1<0x141>(v)); // xor3 o xor7
    else if constexpr (M4 == 8)  return dpp1<0x128>(v);  // row_ror:8 == xor8
    else return v;
}

// general 6-bit xor shuffle on the LDS pipe (0 VALU slots):
// ds_swizzle BitMode for masks 1..31, ds_bpermute for masks with bit5 set.
template<int ML>
__device__ __forceinline__ float shuf(float v, int lane) {
    if constexpr (ML == 0) {
        return v;
    } else if constexpr (ML >= 32) {
        int addr = (lane ^ ML) << 2;   // CSE'd across the 16 uses per gate
        return __int_as_float(__builtin_amdgcn_ds_bpermute(addr, __float_as_int(v)));
    } else {
        return __int_as_float(__builtin_amdgcn_ds_swizzle(
            __float_as_int(v), (ML << 10) | 0x1F));   // xor=ML, and=0x1F
    }
}

// full 64-lane sum, all lanes receive the total.
// permlane*_swap trick: r[0]+r[1] == v + v[lane^K] for every lane (no select).
__device__ __forceinline__ float wred(float v, int lane) {
    v += shuf4<1>(v);
    v += shuf4<2>(v);
    v += shuf4<4>(v);
    v += shuf4<8>(v);
#if __has_builtin(__builtin_amdgcn_permlane16_swap)
    {
        auto r = __builtin_amdgcn_permlane16_swap(__float_as_int(v), __float_as_int(v), false, false);
        v = __int_as_float(r[0]) + __int_as_float(r[1]);
    }
#else
    v += __shfl_xor(v, 16, 64);
#endif
#if __has_builtin(__builtin_amdgcn_permlane32_swap)
    {
        auto r = __builtin_amdgcn_permlane32_swap(__float_as_int(v), __float_as_int(v), false, false);
        v = __int_as_float(r[0]) + __int_as_float(r[1]);
    }
#else
    v += __shfl_xor(v, 32, 64);
#endif
    return v;
}

__device__ __forceinline__ float fast_tanh(float y) {
    float ex = __expf(2.f * y);                       // inf for large y -> t=1
    return 1.f - 2.f * __builtin_amdgcn_rcpf(ex + 1.f);
}

// ---------------- merged RZ*RY gate, shuffle-first, two rows ----------------
// amp_new(x) = L(x)*amp(x) + P(x)*amp(x^M), with
//   L = a0 + i*eta*a1,  P = eta*b0 - i*b1     (a0=cy*cz, a1=cy*sz, b0=sy*cz, b1=sy*sz)
//   eta(x) = +1 iff parity(x & R) == 1; cross-sign parity(M&R)==1 for ALL gates
//   (M = A^l e_b, R = row_b(A^-l) -> R.M = I_bb = 1), giving the uniform -i*b1.
// Shuffles read the PRE-gate state -> they issue first and overlap the local FMAs.
template<int M, int R>
__device__ __forceinline__ void gate_m(float (&srA)[4], float (&siA)[4],
                                       float (&srB)[4], float (&siB)[4],
                                       float a0, float a1, float b0, float b1,
                                       int lane) {
    constexpr int ML = M & 63, MH = (M >> 6) & 3;
    constexpr int RL = R & 63, RH = (R >> 6) & 3;
    bool p0;
    if constexpr (RL == 0)                 p0 = false;
    else if constexpr ((RL & (RL-1)) == 0) p0 = (lane & RL) != 0;
    else                                   p0 = (__popc(lane & RL) & 1) != 0;

    // partner snapshot of PRE-gate state (16 DS ops, two independent chains)
    float prA[4], piA[4], prB[4], piB[4];
#pragma unroll
    for (int hi = 0; hi < 4; hi++) {
        prA[hi] = shuf<ML>(srA[hi ^ MH], lane);
        piA[hi] = shuf<ML>(siA[hi ^ MH], lane);
        prB[hi] = shuf<ML>(srB[hi ^ MH], lane);
        piB[hi] = shuf<ML>(siB[hi ^ MH], lane);
    }

    float ea1 = p0 ? a1 : -a1;
    float eb0 = p0 ? b0 : -b0;

#pragma unroll
    for (int hi = 0; hi < 4; hi++) {
        const bool f = (__builtin_popcount(hi & RH) & 1) != 0;
        float za1 = f ? -ea1 : ea1;    // eta*a1
        float zb0 = f ? -eb0 : eb0;    // eta*b0
        // local part first (overlaps DS latency), partner part last
        float lrA = fmaf(-za1, siA[hi], a0 * srA[hi]);
        float liA = fmaf( za1, srA[hi], a0 * siA[hi]);
        srA[hi] = fmaf( b1, piA[hi], fmaf(zb0, prA[hi], lrA));
        siA[hi] = fmaf(-b1, prA[hi], fmaf(zb0, piA[hi], liA));
        float lrB = fmaf(-za1, siB[hi], a0 * srB[hi]);
        float liB = fmaf( za1, srB[hi], a0 * siB[hi]);
        srB[hi] = fmaf( b1, piB[hi], fmaf(zb0, prB[hi], lrB));
        siB[hi] = fmaf(-b1, prB[hi], fmaf(zb0, piB[hi], liB));
    }
}

__global__ __launch_bounds__(THREADS, 4) void hqcl_kernel(
    const float* __restrict__ x,     // (B,16)
    const float* __restrict__ w1,    // (256,16)
    const float* __restrict__ b1,    // (256)
    const float* __restrict__ w2,    // (8,256)
    const float* __restrict__ b2,    // (8)
    const float* __restrict__ qp,    // (48)
    const float* __restrict__ dw1,   // (256,1)
    const float* __restrict__ db1,   // (256)
    const float* __restrict__ dw2,   // (1,256)
    const float* __restrict__ db2,   // (1)
    float* __restrict__ out, int B)
{
    __shared__ float4 sG4[NGATE];    // (a0,a1,b0,b1) products per gate

    const int t = threadIdx.x;
    if (t < NGATE) {
        float cz, sz, cy, sy;
        __sincosf(qp[2 * t] * 0.5f,     &sz, &cz);
        __sincosf(qp[2 * t + 1] * 0.5f, &sy, &cy);
        sG4[t] = make_float4(cz * cy, sz * cy, cz * sy, sz * sy);
    }
    __syncthreads();

    const int lane = t & 63;
    const int row0 = blockIdx.x * ROWS_PER_BLOCK + (t >> 6) * 2;
    if (row0 >= B) return;
    const int rowB = (row0 + 1 < B) ? row0 + 1 : row0;

    // ---- encoder: h = relu(x @ W1^T + b1), two rows, full hoist (R5 config) ----
    const float4* xA = (const float4*)(x + row0 * FDIM);
    const float4* xB = (const float4*)(x + rowB * FDIM);
    float4 xa0 = xA[0], xa1 = xA[1], xa2 = xA[2], xa3 = xA[3];
    float4 xb0 = xB[0], xb1 = xB[1], xb2 = xB[2], xb3 = xB[3];

    float hA[4], hB[4];
#pragma unroll
    for (int m = 0; m < 4; m++) {
        int j = lane + 64 * m;
        const float4* wp = (const float4*)(w1 + j * FDIM);
        float4 wa = wp[0], wb = wp[1], wc = wp[2], wd = wp[3];
        float bv = b1[j];
        float aA = bv, aB = bv;
        aA = fmaf(xa0.x, wa.x, aA); aA = fmaf(xa0.y, wa.y, aA);
        aA = fmaf(xa0.z, wa.z, aA); aA = fmaf(xa0.w, wa.w, aA);
        aA = fmaf(xa1.x, wb.x, aA); aA = fmaf(xa1.y, wb.y, aA);
        aA = fmaf(xa1.z, wb.z, aA); aA = fmaf(xa1.w, wb.w, aA);
        aA = fmaf(xa2.x, wc.x, aA); aA = fmaf(xa2.y, wc.y, aA);
        aA = fmaf(xa2.z, wc.z, aA); aA = fmaf(xa2.w, wc.w, aA);
        aA = fmaf(xa3.x, wd.x, aA); aA = fmaf(xa3.y, wd.y, aA);
        aA = fmaf(xa3.z, wd.z, aA); aA = fmaf(xa3.w, wd.w, aA);
        aB = fmaf(xb0.x, wa.x, aB); aB = fmaf(xb0.y, wa.y, aB);
        aB = fmaf(xb0.z, wa.z, aB); aB = fmaf(xb0.w, wa.w, aB);
        aB = fmaf(xb1.x, wb.x, aB); aB = fmaf(xb1.y, wb.y, aB);
        aB = fmaf(xb1.z, wb.z, aB); aB = fmaf(xb1.w, wb.w, aB);
        aB = fmaf(xb2.x, wc.x, aB); aB = fmaf(xb2.y, wc.y, aB);
        aB = fmaf(xb2.z, wc.z, aB); aB = fmaf(xb2.w, wc.w, aB);
        aB = fmaf(xb3.x, wd.x, aB); aB = fmaf(xb3.y, wd.y, aB);
        aB = fmaf(xb3.z, wd.z, aB); aB = fmaf(xb3.w, wd.w, aB);
        hA[m] = fmaxf(aA, 0.f);
        hB[m] = fmaxf(aB, 0.f);
    }

    // ---- angles: u = tanh(h @ W2^T + b2)/4 revolutions ----
    float c0A, s0A, c1A, s1A, c0B, s0B, c1B, s1B;
    float plA = 1.f, plB = 1.f;
#pragma unroll
    for (int q = 0; q < NQ; q++) {
        float aA = 0.f, aB = 0.f;
#pragma unroll
        for (int m = 0; m < 4; m++) {
            float wv = w2[q * HDIM + lane + 64 * m];
            aA = fmaf(hA[m], wv, aA);
            aB = fmaf(hB[m], wv, aB);
        }
        aA = wred(aA, lane);
        aB = wred(aB, lane);
        float bq = b2[q];
        float uA = 0.25f * fast_tanh(aA + bq);
        float uB = 0.25f * fast_tanh(aB + bq);
        float svA, cvA, svB, cvB;
        asm("v_sin_f32 %0, %1" : "=v"(svA) : "v"(uA));
        asm("v_cos_f32 %0, %1" : "=v"(cvA) : "v"(uA));
        asm("v_sin_f32 %0, %1" : "=v"(svB) : "v"(uB));
        asm("v_cos_f32 %0, %1" : "=v"(cvB) : "v"(uB));
        if (q == 0)      { c0A = cvA; s0A = svA; c0B = cvB; s0B = svB; }
        else if (q == 1) { c1A = cvA; s1A = svA; c1B = cvB; s1B = svB; }
        else {
            bool bit = (lane >> (7 - q)) & 1;
            plA *= bit ? svA : cvA;
            plB *= bit ? svB : cvB;
        }
    }

    // ---- initial product state: amp index = hi*64 + lane ----
    float srA[4], siA[4], srB[4], siB[4];
    srA[0] = plA * c1A * c0A;  srA[1] = plA * s1A * c0A;
    srA[2] = plA * c1A * s0A;  srA[3] = plA * s1A * s0A;
    srB[0] = plB * c1B * c0B;  srB[1] = plB * s1B * c0B;
    srB[2] = plB * c1B * s0B;  srB[3] = plB * s1B * s0B;
#pragma unroll
    for (int hi = 0; hi < 4; hi++) { siA[hi] = 0.f; siB[hi] = 0.f; }

    // ---- circuit: CX chains folded into per-layer masks (GF(2) relabeling) ----
    // A cols: C1 03 06 0C 18 30 60 C0 ; A^2 cols: 61 C2 05 0A 14 28 50 A0
    // A^-1 rows: FF FE FC F8 F0 E0 C0 7F ; A^-2 rows: AA 55 AB 57 AF 5F BF D5
#define GATE(L, Q, MM, RR) { float4 g4 = sG4[(L)*8 + (Q)]; \
        gate_m<MM, RR>(srA, siA, srB, siB, g4.x, g4.y, g4.z, g4.w, lane); }
    // layer 0 (identity labeling)
    GATE(0,0,0x80,0x80) GATE(0,1,0x40,0x40) GATE(0,2,0x20,0x20) GATE(0,3,0x10,0x10)
    GATE(0,4,0x08,0x08) GATE(0,5,0x04,0x04) GATE(0,6,0x02,0x02) GATE(0,7,0x01,0x01)
    // layer 1 (masks = cols of A, parities = rows of A^-1)
    GATE(1,0,0xC0,0x7F) GATE(1,1,0x60,0xC0) GATE(1,2,0x30,0xE0) GATE(1,3,0x18,0xF0)
    GATE(1,4,0x0C,0xF8) GATE(1,5,0x06,0xFC) GATE(1,6,0x03,0xFE) GATE(1,7,0xC1,0xFF)
    // layer 2 (masks = cols of A^2, parities = rows of A^-2)
    GATE(2,0,0xA0,0xD5) GATE(2,1,0x50,0xBF) GATE(2,2,0x28,0x5F) GATE(2,3,0x14,0xAF)
    GATE(2,4,0x0A,0x57) GATE(2,5,0x05,0xAB) GATE(2,6,0xC2,0x55) GATE(2,7,0x61,0xAA)
#undef GATE

    // ---- <Z_0> with final labeling: sign = parity(x & 0x4C) (row7 of A^-3) ----
    bool pb = (__popc(lane & 0x0C) & 1) != 0;
    float m0A = srA[0]*srA[0] + siA[0]*siA[0] + srA[2]*srA[2] + siA[2]*siA[2];
    float m1A = srA[1]*srA[1] + siA[1]*siA[1] + srA[3]*srA[3] + siA[3]*siA[3];
    float m0B = srB[0]*srB[0] + siB[0]*siB[0] + srB[2]*srB[2] + siB[2]*siB[2];
    float m1B = srB[1]*srB[1] + siB[1]*siB[1] + srB[3]*srB[3] + siB[3]*siB[3];
    float eA = pb ? (m1A - m0A) : (m0A - m1A);
    float eB = pb ? (m1B - m0B) : (m0B - m1B);
    eA = wred(eA, lane);
    eB = wred(eB, lane);

    // ---- decoder (weights shared across rows) ----
    float accA = 0.f, accB = 0.f;
#pragma unroll
    for (int m = 0; m < 4; m++) {
        int j = lane + 64 * m;
        float w1v = dw1[j], bv = db1[j], w2v = dw2[j];
        float dA = fmaxf(fmaf(eA, w1v, bv), 0.f);
        float dB = fmaxf(fmaf(eB, w1v, bv), 0.f);
        accA = fmaf(dA, w2v, accA);
        accB = fmaf(dB, w2v, accB);
    }
    accA = wred(accA, lane);
    accB = wred(accB, lane);
    if (lane == 0) {
        float bb = db2[0];
        out[row0] = 1.f / (1.f + __expf(-(accA + bb)));
        if (row0 + 1 < B)
            out[row0 + 1] = 1.f / (1.f + __expf(-(accB + bb)));
    }
}

extern "C" void kernel_launch(void* const* d_in, const int* in_sizes, int n_in,
                              void* d_out, int out_size, void* d_ws, size_t ws_size,
                              hipStream_t stream) {
    const float* x   = (const float*)d_in[0];
    const float* w1  = (const float*)d_in[1];
    const float* b1  = (const float*)d_in[2];
    const float* w2  = (const float*)d_in[3];
    const float* b2  = (const float*)d_in[4];
    const float* qp  = (const float*)d_in[5];
    const float* dw1 = (const float*)d_in[6];
    const float* db1 = (const float*)d_in[7];
    const float* dw2 = (const float*)d_in[8];
    const float* db2 = (const float*)d_in[9];
    float* out = (float*)d_out;

    const int B = in_sizes[0] / FDIM;
    const int grid = (B + ROWS_PER_BLOCK - 1) / ROWS_PER_BLOCK;
    hqcl_kernel<<<grid, THREADS, 0, stream>>>(x, w1, b1, w2, b2, qp, dw1, db1, dw2, db2, out, B);
}